// Round 2
// baseline (617.804 us; speedup 1.0000x reference)
//
#include <hip/hip_runtime.h>
#include <hip/hip_fp16.h>

typedef _Float16 half8 __attribute__((ext_vector_type(8)));
typedef _Float16 half4 __attribute__((ext_vector_type(4)));
typedef float floatx16 __attribute__((ext_vector_type(16)));

// async global->LDS, 16B per lane; LDS dest is wave-uniform base + lane*16
#define GLDS16(g, l)                                                           \
  __builtin_amdgcn_global_load_lds(                                            \
      (const __attribute__((address_space(1))) void*)(g),                      \
      (__attribute__((address_space(3))) void*)(l), 16, 0, 0)

// ---------------------------------------------------------------------------
// Fused prep. R2: PERSISTENT grid (2048 blocks = 8/CU = 32 waves/CU), each
// block loops over ~13 work-chunks. R0/R1 both hit ~2 TB/s with 13-27k
// single-shot blocks (~2 us life: load-ramp + drain each) regardless of
// per-thread ILP -> theory: per-block pipeline fill/drain dominates.
// Persistent blocks amortize ramp across 13 chunks.
// ---------------------------------------------------------------------------
__device__ inline void mix_coeffs(const float* lv, const float* ml,
                                  float* cmu, float* cn) {
  float m0 = ml[0], m1 = ml[1], m2 = ml[2], m3 = ml[3];
  float mx = fmaxf(fmaxf(m0, m1), fmaxf(m2, m3));
  float e0 = __expf(m0 - mx), e1 = __expf(m1 - mx);
  float e2 = __expf(m2 - mx), e3 = __expf(m3 - mx);
  float inv = 1.0f / (e0 + e1 + e2 + e3);
  cmu[0] = e0 * inv; cmu[1] = e1 * inv; cmu[2] = e2 * inv; cmu[3] = e3 * inv;
  cn[0] = cmu[0] * __expf(0.5f * lv[0]);
  cn[1] = cmu[1] * __expf(0.5f * lv[1]);
  cn[2] = cmu[2] * __expf(0.5f * lv[2]);
  cn[3] = cmu[3] * __expf(0.5f * lv[3]);
}

// one chunk = 256 threads x float4 (contiguous 16B/lane, ideal coalescing)
__device__ inline void do_prep_w(const float* __restrict__ mu,
                                 const float* __restrict__ nz,
                                 const float* lv, const float* ml,
                                 _Float16* __restrict__ out, long count4,
                                 int bid) {
  float cmu[4], cn[4];
  mix_coeffs(lv, ml, cmu, cn);
  long i = (long)bid * 256 + threadIdx.x;  // float4 granule index
  const float4* m4 = (const float4*)mu;
  const float4* n4 = (const float4*)nz;
  // all 8 loads issued back-to-back
  float4 a0 = m4[0 * count4 + i];
  float4 a1 = m4[1 * count4 + i];
  float4 a2 = m4[2 * count4 + i];
  float4 a3 = m4[3 * count4 + i];
  float4 b0 = n4[0 * count4 + i];
  float4 b1 = n4[1 * count4 + i];
  float4 b2 = n4[2 * count4 + i];
  float4 b3 = n4[3 * count4 + i];
  float rx = cmu[0]*a0.x + cn[0]*b0.x + cmu[1]*a1.x + cn[1]*b1.x
           + cmu[2]*a2.x + cn[2]*b2.x + cmu[3]*a3.x + cn[3]*b3.x;
  float ry = cmu[0]*a0.y + cn[0]*b0.y + cmu[1]*a1.y + cn[1]*b1.y
           + cmu[2]*a2.y + cn[2]*b2.y + cmu[3]*a3.y + cn[3]*b3.y;
  float rz = cmu[0]*a0.z + cn[0]*b0.z + cmu[1]*a1.z + cn[1]*b1.z
           + cmu[2]*a2.z + cn[2]*b2.z + cmu[3]*a3.z + cn[3]*b3.z;
  float rw = cmu[0]*a0.w + cn[0]*b0.w + cmu[1]*a1.w + cn[1]*b1.w
           + cmu[2]*a2.w + cn[2]*b2.w + cmu[3]*a3.w + cn[3]*b3.w;
  half4 h = {(_Float16)rx, (_Float16)ry, (_Float16)rz, (_Float16)rw};
  *(half4*)(out + i * 4) = h;
}

__device__ inline void do_prep_b(const float* __restrict__ bmu,
                                 const float* __restrict__ bn,
                                 const float* lv, const float* ml,
                                 float* __restrict__ out, int O, int bid) {
  float cmu[4], cn[4];
  mix_coeffs(lv, ml, cmu, cn);
  int i = bid * 256 + threadIdx.x;
  if (i >= O) return;
  float r = 0.f;
#pragma unroll
  for (int k = 0; k < 4; ++k)
    r += cmu[k] * bmu[k * O + i] + cn[k] * bn[k * O + i];
  out[i] = r;
}

__device__ inline void do_cvt(const float* __restrict__ in,
                              _Float16* __restrict__ out, int bid) {
  long i = ((long)bid * 256 + threadIdx.x) * 4;
  float4 v = *(const float4*)(in + i);
  half4 h = {(_Float16)v.x, (_Float16)v.y, (_Float16)v.z, (_Float16)v.w};
  *(half4*)(out + i) = h;
}

struct PrepArgs {
  const float* x; _Float16* x16;
  const float* wmu0; const float* wn0; const float* wlv0; const float* ml0; _Float16* W0;
  const float* wmu1; const float* wn1; const float* wlv1; const float* ml1; _Float16* W1;
  const float* wmu2; const float* wn2; const float* wlv2; const float* ml2; _Float16* W2;
  const float* bmu0; const float* bn0; const float* blv0; float* b0;
  const float* bmu1; const float* bn1; const float* blv1; float* b1;
  const float* bmu2; const float* bn2; const float* blv2; float* b2;
};

// work-blocks: [0,4096) W0 | [4096,8192) W1 | [8192,10240) W2 |
// [10240,26624) cvt | [26624,26644) biases.  grid = 2048 persistent blocks.
__global__ __launch_bounds__(256) void prep_all(PrepArgs a) {
  for (int wb = blockIdx.x; wb < 26644; wb += 2048) {
    if (wb < 4096) {
      do_prep_w(a.wmu0, a.wn0, a.wlv0, a.ml0, a.W0, 1048576, wb);
    } else if (wb < 8192) {
      do_prep_w(a.wmu1, a.wn1, a.wlv1, a.ml1, a.W1, 1048576, wb - 4096);
    } else if (wb < 10240) {
      do_prep_w(a.wmu2, a.wn2, a.wlv2, a.ml2, a.W2, 524288, wb - 8192);
    } else if (wb < 26624) {
      do_cvt(a.x, a.x16, wb - 10240);
    } else if (wb < 26632) {
      do_prep_b(a.bmu0, a.bn0, a.blv0, a.ml0, a.b0, 2048, wb - 26624);
    } else if (wb < 26640) {
      do_prep_b(a.bmu1, a.bn1, a.blv1, a.ml1, a.b1, 2048, wb - 26632);
    } else {
      do_prep_b(a.bmu2, a.bn2, a.blv2, a.ml2, a.b2, 1024, wb - 26640);
    }
  }
}

// ---------------------------------------------------------------------------
// GEMM: C[M,N] = act(A[M,K] * B[N,K]^T + bias), fp16 in, 32x32x16 MFMA.
// R2: m97-replica config — the measured-912-TF structure for simple
// 2-barrier loops: 128x128 tile, 4 waves (2x2), wave tile 64x64 ->
// acc[2][2] (64 acc VGPR), BK=64, SINGLE 32 KiB LDS buffer,
// stage -> barrier -> compute -> barrier. The vmcnt(0) drain inside
// __syncthreads is covered by INTER-BLOCK overlap: 32 KiB LDS +
// __launch_bounds__(256,3) -> 3 blocks/CU (12 waves/CU), m114-style
// MFMA/VALU co-scheduling across blocks. (R1's 256^2/128KiB explicit
// 2-phase ran 1 block/CU: nothing covered the drain -> 21% of peak.)
//
// LDS layout: rows of 8 granules (16B; BK=64 fp16 = 128B/row), XOR swizzle
// LDS(r,pos) holds global granule gc = pos^(r&7); staging lane-linear
// (GLDS16-compatible), fragment reads conflict-free (verified 0 in R0/R1).
// A-frag (32x32x16): lane holds A[m=l&31][k=(l>>5)*8+j], j=0..7.
// C/D layout (m74/m101): col=lane&31, row=(reg&3)+8*(reg>>2)+4*(lane>>5).
// ---------------------------------------------------------------------------
template <bool RELU, bool OUT_HALF>
__global__ __launch_bounds__(256, 3) void gemm_nt(
    const _Float16* __restrict__ A, const _Float16* __restrict__ B,
    const float* __restrict__ bias, void* __restrict__ Cout,
    int M, int N, int K) {
  __shared__ _Float16 sA[128 * 64];
  __shared__ _Float16 sB[128 * 64];

  const int t = threadIdx.x;
  const int l = t & 63;
  const int w = t >> 6;
  const int wr = w >> 1;   // wave row 0..1 (64 rows each)
  const int wc = w & 1;    // wave col 0..1 (64 cols each)
  // grid: x = col-blocks (fast-varying -> consecutive blocks share A-panel),
  // y = row-blocks
  const long rowBlock = (long)blockIdx.y * 128;
  const long colBlock = (long)blockIdx.x * 128;

  floatx16 acc[2][2] = {};

  // staging source pointers: 4 GLDS/thread for A, 4 for B (1024 granules ea)
  const _Float16* ga[4];
  const _Float16* gb[4];
#pragma unroll
  for (int j = 0; j < 4; ++j) {
    int p = j * 256 + t;
    int r = p >> 3, pos = p & 7;
    int gc = pos ^ (r & 7);
    ga[j] = A + (rowBlock + r) * (long)K + gc * 8;
    gb[j] = B + (colBlock + r) * (long)K + gc * 8;
  }
  char* stA = (char*)sA + w * 1024;  // wave-uniform LDS staging bases
  char* stB = (char*)sB + w * 1024;

  const int rm = l & 31;   // row within 32-tile
  const int kh = l >> 5;   // k-half
  const int sw = rm & 7;   // swizzle key

  for (int k0 = 0; k0 < K; k0 += 64) {
#pragma unroll
    for (int j = 0; j < 4; ++j) GLDS16(ga[j] + k0, stA + j * 4096);
#pragma unroll
    for (int j = 0; j < 4; ++j) GLDS16(gb[j] + k0, stB + j * 4096);
    __syncthreads();
#pragma unroll
    for (int s = 0; s < 4; ++s) {  // four K=16 MFMA steps per BK=64
      const int pos = (s * 2 + kh) ^ sw;
      half8 af[2], bf[2];
#pragma unroll
      for (int rt = 0; rt < 2; ++rt)
        af[rt] = *(const half8*)((const char*)sA +
                                 ((wr * 64 + rt * 32 + rm) * 128 + pos * 16));
#pragma unroll
      for (int ct = 0; ct < 2; ++ct)
        bf[ct] = *(const half8*)((const char*)sB +
                                 ((wc * 64 + ct * 32 + rm) * 128 + pos * 16));
#pragma unroll
      for (int rt = 0; rt < 2; ++rt)
#pragma unroll
        for (int ct = 0; ct < 2; ++ct)
          acc[rt][ct] = __builtin_amdgcn_mfma_f32_32x32x16_f16(
              af[rt], bf[ct], acc[rt][ct], 0, 0, 0);
    }
    __syncthreads();
  }

  // epilogue
  const int cl = l & 31;
  const int rh = (l >> 5) * 4;
#pragma unroll
  for (int rt = 0; rt < 2; ++rt) {
#pragma unroll
    for (int ct = 0; ct < 2; ++ct) {
      const long colg = colBlock + wc * 64 + ct * 32 + cl;
      const float bv = bias[colg];
#pragma unroll
      for (int reg = 0; reg < 16; ++reg) {
        const int rowin = (reg & 3) + 8 * (reg >> 2) + rh;
        const long rowg = rowBlock + wr * 64 + rt * 32 + rowin;
        float v = acc[rt][ct][reg] + bv;
        if (RELU) v = fmaxf(v, 0.0f);
        if (OUT_HALF)
          ((_Float16*)Cout)[rowg * N + colg] = (_Float16)v;
        else
          ((float*)Cout)[rowg * N + colg] = v;
      }
    }
  }
}

// ---------------------------------------------------------------------------
// Row softmax over N=1024, one block per row, one float4 per thread
// ---------------------------------------------------------------------------
__global__ __launch_bounds__(256) void softmax_rows(float* __restrict__ io) {
  const int N = 1024;
  float* p = io + (long)blockIdx.x * N;
  int t = threadIdx.x;
  int w = t >> 6;
  float4 v = ((const float4*)p)[t];
  float m = fmaxf(fmaxf(v.x, v.y), fmaxf(v.z, v.w));
#pragma unroll
  for (int off = 32; off > 0; off >>= 1) m = fmaxf(m, __shfl_xor(m, off));
  __shared__ float red[8];
  if ((t & 63) == 0) red[w] = m;
  __syncthreads();
  m = fmaxf(fmaxf(red[0], red[1]), fmaxf(red[2], red[3]));
  float4 e;
  e.x = __expf(v.x - m); e.y = __expf(v.y - m);
  e.z = __expf(v.z - m); e.w = __expf(v.w - m);
  float s = e.x + e.y + e.z + e.w;
#pragma unroll
  for (int off = 32; off > 0; off >>= 1) s += __shfl_xor(s, off);
  if ((t & 63) == 0) red[4 + w] = s;
  __syncthreads();
  s = red[4] + red[5] + red[6] + red[7];
  float inv = 1.0f / s;
  float4 o = {e.x * inv, e.y * inv, e.z * inv, e.w * inv};
  ((float4*)p)[t] = o;
}

// ---------------------------------------------------------------------------
extern "C" void kernel_launch(void* const* d_in, const int* in_sizes, int n_in,
                              void* d_out, int out_size, void* d_ws,
                              size_t ws_size, hipStream_t stream) {
  char* ws = (char*)d_ws;
  _Float16* x16 = (_Float16*)(ws);              // 33,554,432 B (reused as h1)
  _Float16* h0  = (_Float16*)(ws + 33554432);   // 33,554,432 B
  _Float16* W0  = (_Float16*)(ws + 67108864);   //  8,388,608 B
  _Float16* W1  = (_Float16*)(ws + 75497472);   //  8,388,608 B
  _Float16* W2  = (_Float16*)(ws + 83886080);   //  4,194,304 B
  float* b0 = (float*)(ws + 88080384);          //  8 KB
  float* b1 = (float*)(ws + 88088576);          //  8 KB
  float* b2 = (float*)(ws + 88096768);          //  4 KB

  PrepArgs a;
  a.x = (const float*)d_in[0]; a.x16 = x16;
  a.wmu0 = (const float*)d_in[1];  a.bmu0 = (const float*)d_in[2];
  a.wlv0 = (const float*)d_in[3];  a.blv0 = (const float*)d_in[4];
  a.ml0  = (const float*)d_in[5];
  a.wn0  = (const float*)d_in[6];  a.bn0  = (const float*)d_in[7];
  a.wmu1 = (const float*)d_in[8];  a.bmu1 = (const float*)d_in[9];
  a.wlv1 = (const float*)d_in[10]; a.blv1 = (const float*)d_in[11];
  a.ml1  = (const float*)d_in[12];
  a.wn1  = (const float*)d_in[13]; a.bn1  = (const float*)d_in[14];
  a.wmu2 = (const float*)d_in[15]; a.bmu2 = (const float*)d_in[16];
  a.wlv2 = (const float*)d_in[17]; a.blv2 = (const float*)d_in[18];
  a.ml2  = (const float*)d_in[19];
  a.wn2  = (const float*)d_in[20]; a.bn2  = (const float*)d_in[21];
  a.W0 = W0; a.W1 = W1; a.W2 = W2; a.b0 = b0; a.b1 = b1; a.b2 = b2;

  prep_all<<<2048, 256, 0, stream>>>(a);

  // gemm0: [8192,2048] = x16 @ W0^T   (128x128 tile, grid x=cols, y=rows)
  gemm_nt<true, true><<<dim3(16, 64), 256, 0, stream>>>(
      x16, W0, b0, h0, 8192, 2048, 2048);
  // gemm1: [8192,2048] = h0 @ W1^T
  gemm_nt<true, true><<<dim3(16, 64), 256, 0, stream>>>(
      h0, W1, b1, x16, 8192, 2048, 2048);
  // gemm2: [8192,1024] = h1 @ W2^T
  gemm_nt<false, false><<<dim3(8, 64), 256, 0, stream>>>(
      x16, W2, b2, d_out, 8192, 1024, 2048);
  softmax_rows<<<8192, 256, 0, stream>>>((float*)d_out);
}

// Round 3
// 612.563 us; speedup vs baseline: 1.0086x; 1.0086x over previous
//
#include <hip/hip_runtime.h>
#include <hip/hip_fp16.h>

typedef _Float16 half8 __attribute__((ext_vector_type(8)));
typedef _Float16 half4 __attribute__((ext_vector_type(4)));
typedef float floatx16 __attribute__((ext_vector_type(16)));

// async global->LDS, 16B per lane; LDS dest is wave-uniform base + lane*16
#define GLDS16(g, l)                                                           \
  __builtin_amdgcn_global_load_lds(                                            \
      (const __attribute__((address_space(1))) void*)(g),                      \
      (__attribute__((address_space(3))) void*)(l), 16, 0, 0)

// ---------------------------------------------------------------------------
// Fused prep. R3: DRAM-burst restructure. R0/R1/R2 all hit ~1.9 TB/s with
// 8 concurrent read streams per block (16K live cursors chip-wide > ~4K DRAM
// row buffers -> row thrash, tRC-limited ~2 TB/s). Now: per k-component,
// burst-read 16KB contiguous from mu_k and nz_k (2 active streams/block),
// FMA into float4 accumulators. Same bytes, row-friendly order.
// ---------------------------------------------------------------------------
__device__ inline void mix_coeffs(const float* lv, const float* ml,
                                  float* cmu, float* cn) {
  float m0 = ml[0], m1 = ml[1], m2 = ml[2], m3 = ml[3];
  float mx = fmaxf(fmaxf(m0, m1), fmaxf(m2, m3));
  float e0 = __expf(m0 - mx), e1 = __expf(m1 - mx);
  float e2 = __expf(m2 - mx), e3 = __expf(m3 - mx);
  float inv = 1.0f / (e0 + e1 + e2 + e3);
  cmu[0] = e0 * inv; cmu[1] = e1 * inv; cmu[2] = e2 * inv; cmu[3] = e3 * inv;
  cn[0] = cmu[0] * __expf(0.5f * lv[0]);
  cn[1] = cmu[1] * __expf(0.5f * lv[1]);
  cn[2] = cmu[2] * __expf(0.5f * lv[2]);
  cn[3] = cmu[3] * __expf(0.5f * lv[3]);
}

__device__ inline void fma4(float4& acc, float cm, const float4& a, float cc,
                            const float4& b) {
  acc.x += cm * a.x + cc * b.x;
  acc.y += cm * a.y + cc * b.y;
  acc.z += cm * a.z + cc * b.z;
  acc.w += cm * a.w + cc * b.w;
}

// block covers 1024 float4 (16KB) per k-slice; thread owns 4 granules at
// +0/+256/+512/+768 (consecutive wave-loads are consecutive 1KB lines).
__device__ inline void do_prep_w4(const float* __restrict__ mu,
                                  const float* __restrict__ nz,
                                  const float* lv, const float* ml,
                                  _Float16* __restrict__ out, long count4,
                                  int bid) {
  float cmu[4], cn[4];
  mix_coeffs(lv, ml, cmu, cn);
  long base = (long)bid * 1024 + threadIdx.x;  // float4 granule index
  const float4* m4 = (const float4*)mu;
  const float4* n4 = (const float4*)nz;
  float4 acc0 = {0, 0, 0, 0}, acc1 = {0, 0, 0, 0};
  float4 acc2 = {0, 0, 0, 0}, acc3 = {0, 0, 0, 0};
#pragma unroll
  for (int k = 0; k < 4; ++k) {
    long o = (long)k * count4 + base;
    // 2 streams, 4 consecutive 1KB wave-loads each: DRAM-row friendly
    float4 a0 = m4[o];
    float4 a1 = m4[o + 256];
    float4 a2 = m4[o + 512];
    float4 a3 = m4[o + 768];
    float4 b0 = n4[o];
    float4 b1 = n4[o + 256];
    float4 b2 = n4[o + 512];
    float4 b3 = n4[o + 768];
    float cm = cmu[k], cc = cn[k];
    fma4(acc0, cm, a0, cc, b0);
    fma4(acc1, cm, a1, cc, b1);
    fma4(acc2, cm, a2, cc, b2);
    fma4(acc3, cm, a3, cc, b3);
  }
  half4 h0 = {(_Float16)acc0.x, (_Float16)acc0.y, (_Float16)acc0.z, (_Float16)acc0.w};
  half4 h1 = {(_Float16)acc1.x, (_Float16)acc1.y, (_Float16)acc1.z, (_Float16)acc1.w};
  half4 h2 = {(_Float16)acc2.x, (_Float16)acc2.y, (_Float16)acc2.z, (_Float16)acc2.w};
  half4 h3 = {(_Float16)acc3.x, (_Float16)acc3.y, (_Float16)acc3.z, (_Float16)acc3.w};
  *(half4*)(out + base * 4) = h0;
  *(half4*)(out + (base + 256) * 4) = h1;
  *(half4*)(out + (base + 512) * 4) = h2;
  *(half4*)(out + (base + 768) * 4) = h3;
}

__device__ inline void do_prep_b(const float* __restrict__ bmu,
                                 const float* __restrict__ bn,
                                 const float* lv, const float* ml,
                                 float* __restrict__ out, int O, int bid) {
  float cmu[4], cn[4];
  mix_coeffs(lv, ml, cmu, cn);
  int i = bid * 256 + threadIdx.x;
  if (i >= O) return;
  float r = 0.f;
#pragma unroll
  for (int k = 0; k < 4; ++k)
    r += cmu[k] * bmu[k * O + i] + cn[k] * bn[k * O + i];
  out[i] = r;
}

__device__ inline void do_cvt4(const float* __restrict__ in,
                               _Float16* __restrict__ out, int bid) {
  long base = (long)bid * 1024 + threadIdx.x;
  const float4* in4 = (const float4*)in;
  float4 v0 = in4[base];
  float4 v1 = in4[base + 256];
  float4 v2 = in4[base + 512];
  float4 v3 = in4[base + 768];
  half4 h0 = {(_Float16)v0.x, (_Float16)v0.y, (_Float16)v0.z, (_Float16)v0.w};
  half4 h1 = {(_Float16)v1.x, (_Float16)v1.y, (_Float16)v1.z, (_Float16)v1.w};
  half4 h2 = {(_Float16)v2.x, (_Float16)v2.y, (_Float16)v2.z, (_Float16)v2.w};
  half4 h3 = {(_Float16)v3.x, (_Float16)v3.y, (_Float16)v3.z, (_Float16)v3.w};
  *(half4*)(out + base * 4) = h0;
  *(half4*)(out + (base + 256) * 4) = h1;
  *(half4*)(out + (base + 512) * 4) = h2;
  *(half4*)(out + (base + 768) * 4) = h3;
}

struct PrepArgs {
  const float* x; _Float16* x16;
  const float* wmu0; const float* wn0; const float* wlv0; const float* ml0; _Float16* W0;
  const float* wmu1; const float* wn1; const float* wlv1; const float* ml1; _Float16* W1;
  const float* wmu2; const float* wn2; const float* wlv2; const float* ml2; _Float16* W2;
  const float* bmu0; const float* bn0; const float* blv0; float* b0;
  const float* bmu1; const float* bn1; const float* blv1; float* b1;
  const float* bmu2; const float* bn2; const float* blv2; float* b2;
};

// grid: [0,1024) W0 | [1024,2048) W1 | [2048,2560) W2 | [2560,6656) cvt |
// [6656,6676) biases.  grid = 6676 one-shot blocks.
__global__ __launch_bounds__(256) void prep_all(PrepArgs a) {
  int b = blockIdx.x;
  if (b < 1024) { do_prep_w4(a.wmu0, a.wn0, a.wlv0, a.ml0, a.W0, 1048576, b); return; }
  b -= 1024;
  if (b < 1024) { do_prep_w4(a.wmu1, a.wn1, a.wlv1, a.ml1, a.W1, 1048576, b); return; }
  b -= 1024;
  if (b < 512) { do_prep_w4(a.wmu2, a.wn2, a.wlv2, a.ml2, a.W2, 524288, b); return; }
  b -= 512;
  if (b < 4096) { do_cvt4(a.x, a.x16, b); return; }
  b -= 4096;
  if (b < 8) { do_prep_b(a.bmu0, a.bn0, a.blv0, a.ml0, a.b0, 2048, b); return; }
  b -= 8;
  if (b < 8) { do_prep_b(a.bmu1, a.bn1, a.blv1, a.ml1, a.b1, 2048, b); return; }
  b -= 8;
  do_prep_b(a.bmu2, a.bn2, a.blv2, a.ml2, a.b2, 1024, b);
}

// ---------------------------------------------------------------------------
// GEMM: C[M,N] = act(A[M,K] * B[N,K]^T + bias), fp16 in, 32x32x16 MFMA.
// R3: explicit 2-phase double-buffer at 128x128 (the m228d/m230 measured
// 622-682 TF class): 4 waves (2x2), wave tile 64x64 -> acc[2][2], BK=64,
// LDS = 2 x 32 KiB = 64 KiB -> 2 blocks/CU. Prefetch tile k+1 issued
// BEFORE compute of tile k; ONE __syncthreads per K-step. The other
// resident block covers this block's barrier drain (R2's single-buffer
// serialized stage after compute; R1's 256^2 ran 1 blk/CU: no cover).
// 1D grid + bijective XCD-chunk swizzle (T1): blocks with equal b%8 (same
// XCD) get a contiguous tile chunk -> A/B panels stay in one XCD's L2.
//
// LDS layout per buffer: rows of 8 granules (16B; BK=64 fp16 = 128B/row),
// XOR swizzle LDS(r,pos) holds global granule gc = pos^(r&7); staging is
// lane-linear (GLDS16-compatible), fragment reads conflict-free (verified
// SQ_LDS_BANK_CONFLICT=0 in R0-R2).
// A-frag (32x32x16): lane holds A[m=l&31][k=(l>>5)*8+j], j=0..7.
// C/D layout (m74/m101): col=lane&31, row=(reg&3)+8*(reg>>2)+4*(lane>>5).
// ---------------------------------------------------------------------------
template <bool RELU, bool OUT_HALF>
__global__ __launch_bounds__(256, 2) void gemm2ph(
    const _Float16* __restrict__ A, const _Float16* __restrict__ B,
    const float* __restrict__ bias, void* __restrict__ Cout,
    int M, int N, int K, int nbx) {
  __shared__ _Float16 sA[2][128 * 64];
  __shared__ _Float16 sB[2][128 * 64];

  // bijective XCD-chunk swizzle (nwg % 8 == 0 by construction)
  const int nwg = gridDim.x;
  const int q = nwg >> 3;
  const int swz = (blockIdx.x & 7) * q + (blockIdx.x >> 3);
  const int bx = swz % nbx;  // col-block (fast: consecutive share A-panel)
  const int by = swz / nbx;  // row-block

  const int t = threadIdx.x;
  const int l = t & 63;
  const int w = t >> 6;
  const int wr = w >> 1;   // wave row 0..1 (64 rows each)
  const int wc = w & 1;    // wave col 0..1 (64 cols each)
  const long rowBlock = (long)by * 128;
  const long colBlock = (long)bx * 128;

  floatx16 acc[2][2] = {};

  // staging source pointers: 4 GLDS/thread for A, 4 for B (1024 granules ea)
  const _Float16* ga[4];
  const _Float16* gb[4];
#pragma unroll
  for (int j = 0; j < 4; ++j) {
    int p = j * 256 + t;
    int r = p >> 3, pos = p & 7;
    int gc = pos ^ (r & 7);
    ga[j] = A + (rowBlock + r) * (long)K + gc * 8;
    gb[j] = B + (colBlock + r) * (long)K + gc * 8;
  }

  const int rm = l & 31;   // row within 32-tile
  const int kh = l >> 5;   // k-half
  const int sw = rm & 7;   // swizzle key

  // prologue: stage tile 0 into buffer 0
#pragma unroll
  for (int j = 0; j < 4; ++j) {
    GLDS16(ga[j], (char*)sA[0] + w * 1024 + j * 4096);
    GLDS16(gb[j], (char*)sB[0] + w * 1024 + j * 4096);
  }
  __syncthreads();

  int cur = 0;
  for (int k0 = 0; k0 < K; k0 += 64) {
    // phase 1: issue next tile's async stage (overlaps compute below)
    if (k0 + 64 < K) {
      const int nxt = cur ^ 1;
#pragma unroll
      for (int j = 0; j < 4; ++j) {
        GLDS16(ga[j] + k0 + 64, (char*)sA[nxt] + w * 1024 + j * 4096);
        GLDS16(gb[j] + k0 + 64, (char*)sB[nxt] + w * 1024 + j * 4096);
      }
    }
    // phase 2: compute current tile
#pragma unroll
    for (int s = 0; s < 4; ++s) {  // four K=16 MFMA steps per BK=64
      const int pos = (s * 2 + kh) ^ sw;
      half8 af[2], bf[2];
#pragma unroll
      for (int rt = 0; rt < 2; ++rt)
        af[rt] = *(const half8*)((const char*)sA[cur] +
                                 ((wr * 64 + rt * 32 + rm) * 128 + pos * 16));
#pragma unroll
      for (int ct = 0; ct < 2; ++ct)
        bf[ct] = *(const half8*)((const char*)sB[cur] +
                                 ((wc * 64 + ct * 32 + rm) * 128 + pos * 16));
#pragma unroll
      for (int rt = 0; rt < 2; ++rt)
#pragma unroll
        for (int ct = 0; ct < 2; ++ct)
          acc[rt][ct] = __builtin_amdgcn_mfma_f32_32x32x16_f16(
              af[rt], bf[ct], acc[rt][ct], 0, 0, 0);
    }
    // one barrier per K-step: drains lgkmcnt (buf[cur] reads done before its
    // overwrite next iter) and vmcnt (prefetch into buf[nxt] landed)
    __syncthreads();
    cur ^= 1;
  }

  // epilogue
  const int cl = l & 31;
  const int rh = (l >> 5) * 4;
#pragma unroll
  for (int rt = 0; rt < 2; ++rt) {
#pragma unroll
    for (int ct = 0; ct < 2; ++ct) {
      const long colg = colBlock + wc * 64 + ct * 32 + cl;
      const float bv = bias[colg];
#pragma unroll
      for (int reg = 0; reg < 16; ++reg) {
        const int rowin = (reg & 3) + 8 * (reg >> 2) + rh;
        const long rowg = rowBlock + wr * 64 + rt * 32 + rowin;
        float v = acc[rt][ct][reg] + bv;
        if (RELU) v = fmaxf(v, 0.0f);
        if (OUT_HALF)
          ((_Float16*)Cout)[rowg * N + colg] = (_Float16)v;
        else
          ((float*)Cout)[rowg * N + colg] = v;
      }
    }
  }
}

// ---------------------------------------------------------------------------
// Row softmax over N=1024, one block per row, one float4 per thread
// ---------------------------------------------------------------------------
__global__ __launch_bounds__(256) void softmax_rows(float* __restrict__ io) {
  const int N = 1024;
  float* p = io + (long)blockIdx.x * N;
  int t = threadIdx.x;
  int w = t >> 6;
  float4 v = ((const float4*)p)[t];
  float m = fmaxf(fmaxf(v.x, v.y), fmaxf(v.z, v.w));
#pragma unroll
  for (int off = 32; off > 0; off >>= 1) m = fmaxf(m, __shfl_xor(m, off));
  __shared__ float red[8];
  if ((t & 63) == 0) red[w] = m;
  __syncthreads();
  m = fmaxf(fmaxf(red[0], red[1]), fmaxf(red[2], red[3]));
  float4 e;
  e.x = __expf(v.x - m); e.y = __expf(v.y - m);
  e.z = __expf(v.z - m); e.w = __expf(v.w - m);
  float s = e.x + e.y + e.z + e.w;
#pragma unroll
  for (int off = 32; off > 0; off >>= 1) s += __shfl_xor(s, off);
  if ((t & 63) == 0) red[4 + w] = s;
  __syncthreads();
  s = red[4] + red[5] + red[6] + red[7];
  float inv = 1.0f / s;
  float4 o = {e.x * inv, e.y * inv, e.z * inv, e.w * inv};
  ((float4*)p)[t] = o;
}

// ---------------------------------------------------------------------------
extern "C" void kernel_launch(void* const* d_in, const int* in_sizes, int n_in,
                              void* d_out, int out_size, void* d_ws,
                              size_t ws_size, hipStream_t stream) {
  char* ws = (char*)d_ws;
  _Float16* x16 = (_Float16*)(ws);              // 33,554,432 B (reused as h1)
  _Float16* h0  = (_Float16*)(ws + 33554432);   // 33,554,432 B
  _Float16* W0  = (_Float16*)(ws + 67108864);   //  8,388,608 B
  _Float16* W1  = (_Float16*)(ws + 75497472);   //  8,388,608 B
  _Float16* W2  = (_Float16*)(ws + 83886080);   //  4,194,304 B
  float* b0 = (float*)(ws + 88080384);          //  8 KB
  float* b1 = (float*)(ws + 88088576);          //  8 KB
  float* b2 = (float*)(ws + 88096768);          //  4 KB

  PrepArgs a;
  a.x = (const float*)d_in[0]; a.x16 = x16;
  a.wmu0 = (const float*)d_in[1];  a.bmu0 = (const float*)d_in[2];
  a.wlv0 = (const float*)d_in[3];  a.blv0 = (const float*)d_in[4];
  a.ml0  = (const float*)d_in[5];
  a.wn0  = (const float*)d_in[6];  a.bn0  = (const float*)d_in[7];
  a.wmu1 = (const float*)d_in[8];  a.bmu1 = (const float*)d_in[9];
  a.wlv1 = (const float*)d_in[10]; a.blv1 = (const float*)d_in[11];
  a.ml1  = (const float*)d_in[12];
  a.wn1  = (const float*)d_in[13]; a.bn1  = (const float*)d_in[14];
  a.wmu2 = (const float*)d_in[15]; a.bmu2 = (const float*)d_in[16];
  a.wlv2 = (const float*)d_in[17]; a.blv2 = (const float*)d_in[18];
  a.ml2  = (const float*)d_in[19];
  a.wn2  = (const float*)d_in[20]; a.bn2  = (const float*)d_in[21];
  a.W0 = W0; a.W1 = W1; a.W2 = W2; a.b0 = b0; a.b1 = b1; a.b2 = b2;

  prep_all<<<6676, 256, 0, stream>>>(a);

  // gemm0: [8192,2048] = x16 @ W0^T   (1D grid 64*16=1024, XCD-swizzled)
  gemm2ph<true, true><<<1024, 256, 0, stream>>>(
      x16, W0, b0, h0, 8192, 2048, 2048, 16);
  // gemm1: [8192,2048] = h0 @ W1^T
  gemm2ph<true, true><<<1024, 256, 0, stream>>>(
      h0, W1, b1, x16, 8192, 2048, 2048, 16);
  // gemm2: [8192,1024] = h1 @ W2^T    (64*8=512 blocks)
  gemm2ph<false, false><<<512, 256, 0, stream>>>(
      x16, W2, b2, d_out, 8192, 1024, 2048, 8);
  softmax_rows<<<8192, 256, 0, stream>>>((float*)d_out);
}